// Round 1
// baseline (340.575 us; speedup 1.0000x reference)
//
#include <hip/hip_runtime.h>
#include <hip/hip_bf16.h>

// Problem constants: N=16, M=65536, FIN=32, FOUT=32, K=7
#define N_    16
#define M_    65536
#define FIN_  32
#define FOUT_ 32
#define K_    7

#define BLOCKS_   2048
#define THREADS_  256
#define WAVES_PB_ 4
#define NXCD_     8
#define WAVES_PER_XCD_ ((BLOCKS_ / NXCD_) * WAVES_PB_)   // 1024
#define GROUPS_   (M_ / 16)                              // 4096 groups of 16 m
#define ITERS_    8                                      // 2 n-phases x 4 groups/wave

typedef __bf16 bf16x8 __attribute__((ext_vector_type(8)));
typedef float  f32x4  __attribute__((ext_vector_type(4)));

// ---------------------------------------------------------------------------
// Pass 1: pure streaming fp32 -> bf16 convert, SAME (N,M,FIN) layout.
// (No transpose needed anymore: gathers are now per-(n, m2) 64 B lines.)
// Nontemporal loads: x is dead after this, keep it out of L2/LLC so the
// bf16 copy stays resident for the gather kernel.
// ---------------------------------------------------------------------------
__global__ __launch_bounds__(256)
void convert_kernel(const float* __restrict__ x, __bf16* __restrict__ xb)
{
    const size_t tid = (size_t)blockIdx.x * blockDim.x + threadIdx.x;
    const f32x4* src = (const f32x4*)x + tid * 2;
    const f32x4 v0 = __builtin_nontemporal_load(src);
    const f32x4 v1 = __builtin_nontemporal_load(src + 1);
    bf16x8 b;
    #pragma unroll
    for (int j = 0; j < 4; ++j) b[j] = (__bf16)v0[j];
    #pragma unroll
    for (int j = 0; j < 4; ++j) b[4 + j] = (__bf16)v1[j];
    *(bf16x8*)(xb + tid * 8) = b;
}

// ---------------------------------------------------------------------------
// Pass 2, XCD-local gathers:
//   - MFMA tiling flipped: A-rows = 16 consecutive m (one group), B = w[k],
//     one n per iteration. Gather per (lane,k) = 16 B of a 64 B line inside
//     the 4 MB slice xb[n,:,:].
//   - blockIdx&7 pins each block to an n-pair {2*xcd, 2*xcd+1}; waves sweep
//     all m for n=2*xcd (4 iters), then n=2*xcd+1 (4 iters). At any time an
//     XCD's gathers hit a 4 MB working set == its private L2.
//   - Writes: 2 KB fully contiguous per wave-iteration, nontemporal so the
//     131 MB write-once stream doesn't evict the gather slice.
//   - B-fragments live in LDS (14 KB) to keep VGPRs under the 4-wave cap
//     (idx/iv are per-lane now, costing VGPRs the old scalar path didn't).
// ---------------------------------------------------------------------------
__global__ __launch_bounds__(256, 4)
void gfc_xcd_kernel(const __bf16* __restrict__ xb,
                    const float* __restrict__ w,
                    const float* __restrict__ bias,
                    const int*   __restrict__ il,
                    const float* __restrict__ iv,
                    float* __restrict__ out)
{
    __shared__ __bf16 wlds[K_ * 2 * 64 * 8];   // [k][h][lane][8] = 14 KB

    const int lane = threadIdx.x & 63;
    const int col  = lane & 15;   // A-row (m offset in group) / C-col (o)
    const int kgrp = lane >> 4;   // 8-wide f-chunk

    // Stage B fragments once per block: frag[k][h][lane][j] = w[k][kg*8+j][h*16+c]
    for (int t = threadIdx.x; t < K_ * 2 * 64; t += THREADS_) {
        const int l  = t & 63;
        const int h  = (t >> 6) & 1;
        const int k  = t >> 7;
        const int c  = l & 15;
        const int kg = l >> 4;
        const float* wp = w + (size_t)k * (FIN_ * FOUT_)
                            + (size_t)(kg * 8) * FOUT_ + h * 16 + c;
        bf16x8 b;
        #pragma unroll
        for (int j = 0; j < 8; ++j) b[j] = (__bf16)wp[j * FOUT_];
        *(bf16x8*)(wlds + (size_t)t * 8) = b;
    }
    __syncthreads();

    const float b_lo = bias[col];
    const float b_hi = bias[16 + col];

    const int xcd  = blockIdx.x & (NXCD_ - 1);
    const int widx = (blockIdx.x >> 3) * WAVES_PB_ + (threadIdx.x >> 6);  // 0..1023

    // iteration it: n = xcd*2 + (it>>2), group g = widx*4 + (it&3), lane m = g*16+col
    int   idxs[K_];
    float ivs[K_];
    {
        const int m0 = (widx * 4) * 16 + col;
        #pragma unroll
        for (int k = 0; k < K_; ++k) {
            idxs[k] = il[m0 * K_ + k];
            ivs[k]  = iv[m0 * K_ + k];
        }
    }
    bf16x8 raw[K_];
    {
        const __bf16* xn = xb + (size_t)(xcd * 2) * (M_ * FIN_);
        #pragma unroll
        for (int k = 0; k < K_; ++k)
            raw[k] = *(const bf16x8*)(xn + (size_t)idxs[k] * FIN_ + kgrp * 8);
    }

    for (int it = 0; it < ITERS_; ++it) {
        const bool has_next = (it + 1) < ITERS_;

        // 1) Next iteration's per-lane idx/iv loads (full compute of latency budget).
        int   idxn[K_];
        float ivn[K_];
        if (has_next) {
            const int it2 = it + 1;
            const int mn  = (widx * 4 + (it2 & 3)) * 16 + col;
            #pragma unroll
            for (int k = 0; k < K_; ++k) {
                idxn[k] = il[mn * K_ + k];
                ivn[k]  = iv[mn * K_ + k];
            }
        }

        // 2) Compute with gathers issued one iteration ago.
        f32x4 acc0 = {0.f, 0.f, 0.f, 0.f};
        f32x4 acc1 = {0.f, 0.f, 0.f, 0.f};
        #pragma unroll
        for (int k = 0; k < K_; ++k) {
            const float ivk = ivs[k];
            bf16x8 a;
            #pragma unroll
            for (int j = 0; j < 8; ++j)
                a[j] = (__bf16)((float)raw[k][j] * ivk);
            const bf16x8 bf0 = *(const bf16x8*)(wlds + ((k * 2 + 0) * 64 + lane) * 8);
            const bf16x8 bf1 = *(const bf16x8*)(wlds + ((k * 2 + 1) * 64 + lane) * 8);
            acc0 = __builtin_amdgcn_mfma_f32_16x16x32_bf16(a, bf0, acc0, 0, 0, 0);
            acc1 = __builtin_amdgcn_mfma_f32_16x16x32_bf16(a, bf1, acc1, 0, 0, 0);
        }

        // 3) raw[] consumed — issue next iteration's gathers (overlap stores + next VALU).
        if (has_next) {
            const int it2 = it + 1;
            const int nn  = xcd * 2 + (it2 >> 2);
            const __bf16* xn = xb + (size_t)nn * (M_ * FIN_);
            #pragma unroll
            for (int k = 0; k < K_; ++k)
                raw[k] = *(const bf16x8*)(xn + (size_t)idxn[k] * FIN_ + kgrp * 8);
            #pragma unroll
            for (int k = 0; k < K_; ++k) { idxs[k] = idxn[k]; ivs[k] = ivn[k]; }
        }

        // 4) Epilogue: D row = m offset (kgrp*4+r), D col = o. 2 KB contiguous/wave.
        const int n_cur = xcd * 2 + (it >> 2);
        const int mb    = (widx * 4 + (it & 3)) * 16;
        #pragma unroll
        for (int r = 0; r < 4; ++r) {
            float* op = out + ((size_t)n_cur * M_ + (size_t)(mb + kgrp * 4 + r)) * FOUT_;
            __builtin_nontemporal_store(acc0[r] + b_lo, op + col);
            __builtin_nontemporal_store(acc1[r] + b_hi, op + 16 + col);
        }
    }
}

// ---------------------------------------------------------------------------
// Fallback (round-1 kernel) if ws_size is too small for the bf16 staging.
// ---------------------------------------------------------------------------
__global__ __launch_bounds__(256, 4)
void gfc_fallback_kernel(const float* __restrict__ x,
                         const float* __restrict__ w,
                         const float* __restrict__ bias,
                         const int*   __restrict__ index_list,
                         const float* __restrict__ index_value,
                         float* __restrict__ out)
{
    const int lane  = threadIdx.x & 63;
    const int col   = lane & 15;
    const int kgrp  = lane >> 4;

    const int waves_per_block = blockDim.x >> 6;
    const int wave_id     = blockIdx.x * waves_per_block + (threadIdx.x >> 6);
    const int total_waves = gridDim.x * waves_per_block;

    bf16x8 bfrag[K_][2];
    #pragma unroll
    for (int k = 0; k < K_; ++k) {
        #pragma unroll
        for (int h = 0; h < 2; ++h) {
            const float* wp = w + (size_t)k * (FIN_ * FOUT_)
                                + (size_t)(kgrp * 8) * FOUT_ + h * 16 + col;
            bf16x8 b;
            #pragma unroll
            for (int j = 0; j < 8; ++j)
                b[j] = (__bf16)wp[j * FOUT_];
            bfrag[k][h] = b;
        }
    }
    const float b_lo = bias[col];
    const float b_hi = bias[16 + col];

    for (int m = wave_id; m < M_; m += total_waves) {
        f32x4 acc0 = {0.f, 0.f, 0.f, 0.f};
        f32x4 acc1 = {0.f, 0.f, 0.f, 0.f};

        #pragma unroll
        for (int k = 0; k < K_; ++k) {
            const int   m2  = index_list[m * K_ + k];
            const float ivk = index_value[m * K_ + k];
            const float* ap = x + ((size_t)col * M_ + (size_t)m2) * FIN_ + kgrp * 8;
            const float4 v0 = *(const float4*)(ap);
            const float4 v1 = *(const float4*)(ap + 4);
            const float av[8] = {v0.x, v0.y, v0.z, v0.w, v1.x, v1.y, v1.z, v1.w};
            bf16x8 a;
            #pragma unroll
            for (int j = 0; j < 8; ++j)
                a[j] = (__bf16)(av[j] * ivk);
            acc0 = __builtin_amdgcn_mfma_f32_16x16x32_bf16(a, bfrag[k][0], acc0, 0, 0, 0);
            acc1 = __builtin_amdgcn_mfma_f32_16x16x32_bf16(a, bfrag[k][1], acc1, 0, 0, 0);
        }

        #pragma unroll
        for (int r = 0; r < 4; ++r) {
            const int n = kgrp * 4 + r;
            const size_t base = ((size_t)n * M_ + (size_t)m) * FOUT_;
            out[base + col]      = acc0[r] + b_lo;
            out[base + 16 + col] = acc1[r] + b_hi;
        }
    }
}

extern "C" void kernel_launch(void* const* d_in, const int* in_sizes, int n_in,
                              void* d_out, int out_size, void* d_ws, size_t ws_size,
                              hipStream_t stream) {
    const float* x    = (const float*)d_in[0];  // (N, M, FIN) fp32
    const float* w    = (const float*)d_in[1];  // (K, FIN, FOUT) fp32
    const float* bias = (const float*)d_in[2];  // (FOUT,) fp32
    const int*   il   = (const int*)  d_in[3];  // (M*K,) int32
    const float* iv   = (const float*)d_in[4];  // (M, K) fp32
    float* out = (float*)d_out;                 // (N, M, FOUT) fp32

    const size_t ws_needed = (size_t)M_ * N_ * FIN_ * sizeof(__bf16);  // 64 MB
    if (ws_size >= ws_needed) {
        __bf16* xb = (__bf16*)d_ws;
        const int t_total = N_ * M_ * FIN_ / 8;               // 4.19M threads
        hipLaunchKernelGGL(convert_kernel, dim3(t_total / 256), dim3(256), 0, stream,
                           x, xb);
        hipLaunchKernelGGL(gfc_xcd_kernel, dim3(BLOCKS_), dim3(THREADS_), 0, stream,
                           xb, w, bias, il, iv, out);
    } else {
        hipLaunchKernelGGL(gfc_fallback_kernel, dim3(2048), dim3(256), 0, stream,
                           x, w, bias, il, iv, out);
    }
}